// Round 8
// baseline (338.780 us; speedup 1.0000x reference)
//
#include <hip/hip_runtime.h>

#define TT 8
#define NN 2048
#define SS 8192
#define MM (NN * SS)   // 16777216 elements

// Bernoulli integer thresholds: p * 2^23 (all probabilities are dyadic k/128)
#define TH_CAP10  655360u    // 10/128 * 2^23  (ucapture, uminus)
#define TH_SEARCH 65536u     //  1/128 * 2^23
#define TH_BACK   6291456u   // 96/128 * 2^23
#define TH_MIN    262144u    //  4/128 * 2^23

#define PASSES 3   // DIAGNOSTIC: 3 identical passes so this dispatch enters the
                   // rocprof top-5 (fills are ~310us). Output identical each
                   // pass; deterministic. Next round reverts to 1 pass.

struct KeyPack { unsigned k[20]; };

__host__ __device__ __forceinline__ void tf2x32(unsigned k0, unsigned k1,
                                                unsigned x0, unsigned x1,
                                                unsigned& o0, unsigned& o1) {
  const unsigned ks2 = k0 ^ k1 ^ 0x1BD11BDAu;
  x0 += k0; x1 += k1;
#define TFR(r) { x0 += x1; x1 = (x1 << (r)) | (x1 >> (32 - (r))); x1 ^= x0; }
  TFR(13) TFR(15) TFR(26) TFR(6)
  x0 += k1;  x1 += ks2 + 1u;
  TFR(17) TFR(29) TFR(16) TFR(24)
  x0 += ks2; x1 += k0 + 2u;
  TFR(13) TFR(15) TFR(26) TFR(6)
  x0 += k0;  x1 += k1 + 3u;
  TFR(17) TFR(29) TFR(16) TFR(24)
  x0 += k1;  x1 += ks2 + 4u;
  TFR(13) TFR(15) TFR(26) TFR(6)
  x0 += ks2; x1 += k0 + 5u;
#undef TFR
  o0 = x0; o1 = x1;
}

__global__ __launch_bounds__(256) void ModSTDP_58823872086838_kernel(
    const int* __restrict__ inS,    // [T, N, S] int32 0/1
    const int* __restrict__ outS,   // [T, N]    int32 0/1
    const float* __restrict__ W,    // [N, S]
    float* __restrict__ out,        // [N, S]
    KeyPack kp)
{
  const unsigned tid = blockIdx.x * blockDim.x + threadIdx.x;

#pragma unroll 1
  for (int pass = 0; pass < PASSES; ++pass) {
    unsigned base = tid << 2;                 // 4 elements per thread
    // Opaque-ify base each pass: compiler cannot prove passes identical, so
    // all loads are re-issued (defeats cross-pass CSE/LICM — DCE rule).
    asm volatile("" : "+v"(base));
    const unsigned n = base >> 13;            // row (S = 8192 = 2^13)

    int osum = 0;
#pragma unroll
    for (int t = 0; t < TT; ++t) osum += outS[t * NN + n];
    const int  ot   = 8 - osum;
    const bool outF = ot < 8;

    const float4 w4 = *reinterpret_cast<const float4*>(W + base);

    int c0 = 0, c1 = 0, c2 = 0, c3 = 0;
#pragma unroll
    for (int t = 0; t < TT; ++t) {
      const int4 sp = *reinterpret_cast<const int4*>(inS + (size_t)t * MM + base);
      c0 += sp.x; c1 += sp.y; c2 += sp.z; c3 += sp.w;
    }
    const int   cnt[4] = {c0, c1, c2, c3};
    const float wv[4]  = {w4.x, w4.y, w4.z, w4.w};
    float res[4];

#pragma unroll
    for (int e = 0; e < 4; ++e) {
      const unsigned j = base + (unsigned)e;
      const float w = fminf(fmaxf(wv[e], 0.0f), 8.0f);
      const int  it  = 8 - cnt[e];
      const bool inF = it < 8;
      const bool b1 = inF && outF && (it <= ot);
      const bool b2 = inF && outF && (it > ot);
      const bool b3 = inF && !outF;
      const bool active = inF || outF;

      // p_plus / p_minus exactly as XLA (no FMA contraction)
      const float wn = w * 0.125f;
      const float pp = __fmul_rn(wn, __fsub_rn(2.0f, wn));
      const float pm = __fmul_rn(__fsub_rn(1.0f, wn), __fadd_rn(1.0f, wn));

      const bool useP = b1 || b3;             // needs fplus, else fminus
      const float    pA  = useP ? pp : pm;
      const unsigned ka0 = useP ? kp.k[0] : kp.k[2];
      const unsigned ka1 = useP ? kp.k[1] : kp.k[3];

      const unsigned kb0 = b1 ? kp.k[4]  : (b2 ? kp.k[6]  : (b3 ? kp.k[8]  : kp.k[10]));
      const unsigned kb1 = b1 ? kp.k[5]  : (b2 ? kp.k[7]  : (b3 ? kp.k[9]  : kp.k[11]));
      const unsigned thB = (b1 || b2) ? TH_CAP10 : (b3 ? TH_SEARCH : TH_BACK);
      const unsigned kc0 = b1 ? kp.k[12] : (b2 ? kp.k[14] : (b3 ? kp.k[16] : kp.k[18]));
      const unsigned kc1 = b1 ? kp.k[13] : (b2 ? kp.k[15] : (b3 ? kp.k[17] : kp.k[19]));

      unsigned a0, a1, bb0, bb1, cc0, cc1;
      tf2x32(ka0, ka1, 0u, j, a0, a1);
      const unsigned bitsA = a0 ^ a1;         // partitionable: x0 ^ x1
      const float u = __uint_as_float((bitsA >> 9) | 0x3f800000u) - 1.0f;
      const bool fab = u < pA;

      tf2x32(kb0, kb1, 0u, j, bb0, bb1);
      const bool gate = (((bb0 ^ bb1) >> 9) < thB);

      tf2x32(kc0, kc1, 0u, j, cc0, cc1);
      const bool um = (((cc0 ^ cc1) >> 9) < TH_MIN);

      const bool doit = active && gate && (fab || um);
      const float sgn = (b2 || (!inF)) ? -1.0f : 1.0f;   // minus/backoff: -1
      res[e] = doit ? (w + sgn) : w;
    }

    *reinterpret_cast<float4*>(out + base) =
        make_float4(res[0], res[1], res[2], res[3]);
  }
}

extern "C" void kernel_launch(void* const* d_in, const int* in_sizes, int n_in,
                              void* d_out, int out_size, void* d_ws, size_t ws_size,
                              hipStream_t stream) {
  const int*   inS  = (const int*)d_in[0];
  const int*   outS = (const int*)d_in[1];
  const float* W    = (const float*)d_in[2];
  float*       out  = (float*)d_out;

  // Host-side key derivation (pure arithmetic — graph-capture safe).
  // jax.random.key(42) -> (0, 42). Fold-like split (threefry_partitionable):
  // rk[i] = threefry(key, (0, i));  k7{a,b,c} = threefry(rk7, (0, {0,1,2}))
  KeyPack kp;
  {
    unsigned rk[16];
    for (unsigned i = 0; i < 8; ++i) {
      unsigned o0, o1;
      tf2x32(0u, 42u, 0u, i, o0, o1);
      rk[2 * i] = o0; rk[2 * i + 1] = o1;
    }
    for (int i = 0; i < 14; ++i) kp.k[i] = rk[i];      // rk0..rk6
    for (unsigned i = 0; i < 3; ++i) {
      unsigned o0, o1;
      tf2x32(rk[14], rk[15], 0u, i, o0, o1);
      kp.k[14 + 2 * i] = o0; kp.k[15 + 2 * i] = o1;
    }
  }

  const int threads = MM / 4;
  dim3 block(256), grid(threads / 256);
  ModSTDP_58823872086838_kernel<<<grid, block, 0, stream>>>(inS, outS, W, out, kp);
}

// Round 9
// 130.647 us; speedup vs baseline: 2.5931x; 2.5931x over previous
//
#include <hip/hip_runtime.h>

#define TT 8
#define NN 2048
#define SS 8192
#define MM (NN * SS)   // 16777216 elements

// Bernoulli integer thresholds: p * 2^23 (all probabilities are dyadic k/128)
#define TH_CAP10  655360u    // 10/128 * 2^23  (ucapture, uminus)
#define TH_SEARCH 65536u     //  1/128 * 2^23
#define TH_BACK   6291456u   // 96/128 * 2^23
#define TH_MIN    262144u    //  4/128 * 2^23

typedef int      __attribute__((ext_vector_type(4))) intx4;
typedef float    __attribute__((ext_vector_type(4))) floatx4;
typedef unsigned __attribute__((ext_vector_type(4))) uintx4;
typedef unsigned __attribute__((ext_vector_type(2))) uintx2;

// 4 branch rows x 40 words. Row layout:
//  [0:12)  draw-A (fplus/fminus) round-key schedule
//  [12:24) draw-B (gate)        round-key schedule
//  [24:36) draw-C (umin)        round-key schedule
//  [36] thB  [37] sgn_bits  [38:40) pad
// Stride 40 words = 160 B -> rows start at banks {0,8,16,24}: the <=4
// distinct per-lane addresses of each ds_read_b128 hit disjoint banks
// (conflict-free broadcast).
struct Tbl { unsigned v[160]; };

// 1-op rotate: v_alignbit_b32 dst = ((hi:lo) >> s)[31:0]; rotl(x,r)=rotr(x,32-r)
#if __has_builtin(__builtin_amdgcn_alignbit)
#define ROTL(x, r) __builtin_amdgcn_alignbit((x), (x), 32u - (r))
#else
#define ROTL(x, r) (((x) << (r)) | ((x) >> (32 - (r))))
#endif

#define R4(x0, x1, ra, rb, rc, rd)                   \
  x0 += x1; x1 = ROTL(x1, ra); x1 ^= x0;             \
  x0 += x1; x1 = ROTL(x1, rb); x1 ^= x0;             \
  x0 += x1; x1 = ROTL(x1, rc); x1 ^= x0;             \
  x0 += x1; x1 = ROTL(x1, rd); x1 ^= x0;

// Threefry-2x32 on counter (0, j) with a precomputed injection schedule
// s0..s2 (12 words: all ks2/+1..+5 arithmetic done on host). Returns x0^x1.
__device__ __forceinline__ unsigned tf_sched(uintx4 s0, uintx4 s1, uintx4 s2,
                                             unsigned j) {
  unsigned x0 = s0.x;            // 0 + k0
  unsigned x1 = j + s0.y;        // j + k1
  R4(x0, x1, 13, 15, 26, 6)
  x0 += s0.z; x1 += s0.w;        // (k1, ks2+1)
  R4(x0, x1, 17, 29, 16, 24)
  x0 += s1.x; x1 += s1.y;        // (ks2, k0+2)
  R4(x0, x1, 13, 15, 26, 6)
  x0 += s1.z; x1 += s1.w;        // (k0, k1+3)
  R4(x0, x1, 17, 29, 16, 24)
  x0 += s2.x; x1 += s2.y;        // (k1, ks2+4)
  R4(x0, x1, 13, 15, 26, 6)
  x0 += s2.z; x1 += s2.w;        // (ks2, k0+5)
  return x0 ^ x1;                // partitionable random_bits: x0 ^ x1
}

// Host-side full Threefry (key derivation only).
static void tf2x32_host(unsigned k0, unsigned k1, unsigned x0, unsigned x1,
                        unsigned& o0, unsigned& o1) {
  const unsigned ks2 = k0 ^ k1 ^ 0x1BD11BDAu;
  x0 += k0; x1 += k1;
#define TFRH(r) { x0 += x1; x1 = (x1 << (r)) | (x1 >> (32 - (r))); x1 ^= x0; }
  TFRH(13) TFRH(15) TFRH(26) TFRH(6)
  x0 += k1;  x1 += ks2 + 1u;
  TFRH(17) TFRH(29) TFRH(16) TFRH(24)
  x0 += ks2; x1 += k0 + 2u;
  TFRH(13) TFRH(15) TFRH(26) TFRH(6)
  x0 += k0;  x1 += k1 + 3u;
  TFRH(17) TFRH(29) TFRH(16) TFRH(24)
  x0 += k1;  x1 += ks2 + 4u;
  TFRH(13) TFRH(15) TFRH(26) TFRH(6)
  x0 += ks2; x1 += k0 + 5u;
#undef TFRH
  o0 = x0; o1 = x1;
}

__global__ __launch_bounds__(256) void ModSTDP_58823872086838_kernel(
    const int* __restrict__ inS,    // [T, N, S] int32 0/1
    const int* __restrict__ outS,   // [T, N]    int32 0/1
    const float* __restrict__ W,    // [N, S]
    float* __restrict__ out,        // [N, S]
    Tbl tb)
{
  __shared__ __align__(16) unsigned tbl[160];
  if (threadIdx.x < 160) tbl[threadIdx.x] = tb.v[threadIdx.x];
  __syncthreads();

  const unsigned tid  = blockIdx.x * blockDim.x + threadIdx.x;
  const unsigned base = tid << 2;               // 4 elements per thread
  const unsigned n    = base >> 13;             // row (S = 8192 = 2^13)

  // Row output-spike count: wave-uniform loads (64 KB table, L1/L2-hot)
  int osum = 0;
#pragma unroll
  for (int t = 0; t < TT; ++t) osum += outS[t * NN + n];
  const bool outF = osum > 0;

  const floatx4 w4 = *reinterpret_cast<const floatx4*>(W + base);

  intx4 sp[TT];
#pragma unroll
  for (int t = 0; t < TT; ++t)
    sp[t] = *reinterpret_cast<const intx4*>(inS + (size_t)t * MM + base);

  int cnt[4] = {0, 0, 0, 0};
#pragma unroll
  for (int t = 0; t < TT; ++t) {
#pragma unroll
    for (int e = 0; e < 4; ++e) cnt[e] += sp[t][e];
  }

  float res[4];
#pragma unroll
  for (int e = 0; e < 4; ++e) {
    const unsigned j = base + (unsigned)e;
    const float w = fminf(fmaxf(w4[e], 0.0f), 8.0f);
    const int c = cnt[e];
    const bool inF = c > 0;
    const bool active = inF | outF;
    // branch index: 0=capture 1=minus 2=search 3=backoff
    // (in_t <= out_t) <=> (8-c <= 8-o) <=> (c >= o)
    const unsigned idx = inF ? (outF ? ((c >= osum) ? 0u : 1u) : 2u) : 3u;
    const unsigned* row = tbl + idx * 40u;

    // p_plus / p_minus exactly as XLA (no FMA contraction)
    const float wn = w * 0.125f;
    const float pp = __fmul_rn(wn, __fsub_rn(2.0f, wn));
    const float pm = __fmul_rn(__fsub_rn(1.0f, wn), __fadd_rn(1.0f, wn));
    const float pA = (idx & 1u) ? pm : pp;   // odd rows use fminus

    // Draw A: fplus/fminus (reuse s-regs across draws to bound VGPR use)
    uintx4 s0 = *reinterpret_cast<const uintx4*>(row);
    uintx4 s1 = *reinterpret_cast<const uintx4*>(row + 4);
    uintx4 s2 = *reinterpret_cast<const uintx4*>(row + 8);
    const unsigned bitsA = tf_sched(s0, s1, s2, j);
    const float u = __uint_as_float((bitsA >> 9) | 0x3f800000u) - 1.0f;
    const bool fab = u < pA;

    // Draw B: gate (ucapture/uminus/usearch/ubackoff)
    s0 = *reinterpret_cast<const uintx4*>(row + 12);
    s1 = *reinterpret_cast<const uintx4*>(row + 16);
    s2 = *reinterpret_cast<const uintx4*>(row + 20);
    const uintx2 tc = *reinterpret_cast<const uintx2*>(row + 36);
    const unsigned bitsB = tf_sched(s0, s1, s2, j);
    const bool gate = (bitsB >> 9) < tc.x;

    // Draw C: umin
    s0 = *reinterpret_cast<const uintx4*>(row + 24);
    s1 = *reinterpret_cast<const uintx4*>(row + 28);
    s2 = *reinterpret_cast<const uintx4*>(row + 32);
    const unsigned bitsC = tf_sched(s0, s1, s2, j);
    const bool um = (bitsC >> 9) < TH_MIN;

    const bool doit = active & gate & (fab | um);
    res[e] = doit ? __fadd_rn(w, __uint_as_float(tc.y)) : w;
  }

  floatx4 r;
  r.x = res[0]; r.y = res[1]; r.z = res[2]; r.w = res[3];
  __builtin_nontemporal_store(r, reinterpret_cast<floatx4*>(out + base));
}

extern "C" void kernel_launch(void* const* d_in, const int* in_sizes, int n_in,
                              void* d_out, int out_size, void* d_ws, size_t ws_size,
                              hipStream_t stream) {
  const int*   inS  = (const int*)d_in[0];
  const int*   outS = (const int*)d_in[1];
  const float* W    = (const float*)d_in[2];
  float*       out  = (float*)d_out;

  // Host-side key derivation (pure arithmetic — graph-capture safe).
  // jax.random.key(42) -> (0, 42). Fold-like split (threefry_partitionable):
  // rk[i] = threefry(key, (0, i));  k7{a,b,c} = threefry(rk7, (0, {0,1,2}))
  unsigned kp[20];
  {
    unsigned rk[16];
    for (unsigned i = 0; i < 8; ++i) {
      unsigned o0, o1;
      tf2x32_host(0u, 42u, 0u, i, o0, o1);
      rk[2 * i] = o0; rk[2 * i + 1] = o1;
    }
    for (int i = 0; i < 14; ++i) kp[i] = rk[i];      // rk0..rk6
    for (unsigned i = 0; i < 3; ++i) {
      unsigned o0, o1;
      tf2x32_host(rk[14], rk[15], 0u, i, o0, o1);
      kp[14 + 2 * i] = o0; kp[15 + 2 * i] = o1;
    }
  }

  // Emit the 12-word injection schedule for key (K0,K1):
  // inj0=(K0,K1) inj1=(K1,ks2+1) inj2=(ks2,K0+2) inj3=(K0,K1+3)
  // inj4=(K1,ks2+4) inj5=(ks2,K0+5)
  auto emit = [](unsigned* d, unsigned K0, unsigned K1) {
    const unsigned ks2 = K0 ^ K1 ^ 0x1BD11BDAu;
    d[0] = K0;  d[1] = K1;       d[2]  = K1;  d[3]  = ks2 + 1u;
    d[4] = ks2; d[5] = K0 + 2u;  d[6]  = K0;  d[7]  = K1 + 3u;
    d[8] = K1;  d[9] = ks2 + 4u; d[10] = ks2; d[11] = K0 + 5u;
  };

  // rows: {drawA keys, drawB keys, drawC keys, thB, sgn}
  // row0 capture : fplus(kp0,1),  ucap(kp4,5),    umin1(kp12,13), CAP10, +1
  // row1 minus   : fminus(kp2,3), uminus(kp6,7),  umin2(kp14,15), CAP10, -1
  // row2 search  : fplus(kp0,1),  usearch(kp8,9), umin3(kp16,17), SEARCH,+1
  // row3 backoff : fminus(kp2,3), uback(kp10,11), umin4(kp18,19), BACK,  -1
  Tbl tb;
  const unsigned rowspec[4][8] = {
    {0, 1, 4, 5, 12, 13, TH_CAP10,  0x3f800000u},
    {2, 3, 6, 7, 14, 15, TH_CAP10,  0xbf800000u},
    {0, 1, 8, 9, 16, 17, TH_SEARCH, 0x3f800000u},
    {2, 3, 10, 11, 18, 19, TH_BACK, 0xbf800000u},
  };
  for (int r = 0; r < 4; ++r) {
    unsigned* d = tb.v + r * 40;
    emit(d,      kp[rowspec[r][0]], kp[rowspec[r][1]]);
    emit(d + 12, kp[rowspec[r][2]], kp[rowspec[r][3]]);
    emit(d + 24, kp[rowspec[r][4]], kp[rowspec[r][5]]);
    d[36] = rowspec[r][6];
    d[37] = rowspec[r][7];
    d[38] = 0; d[39] = 0;
  }

  const int threads = MM / 4;
  dim3 block(256), grid(threads / 256);
  ModSTDP_58823872086838_kernel<<<grid, block, 0, stream>>>(inS, outS, W, out, tb);
}